// Round 5
// baseline (739.551 us; speedup 1.0000x reference)
//
#include <hip/hip_runtime.h>
#include <hip/hip_bf16.h>
#include <cmath>
#include <cstdint>

// AttentionPoolingAggregator — MI355X round 5
//  * GEMM: M-tile 64 -> 32, LDS 16.9 KB, launch_bounds(256,4) => 4 blocks/CU
//    (16 waves/CU) for latency hiding. Everything else unchanged from round 4.

#define H 256

typedef __attribute__((ext_vector_type(8))) short bfrag;  // 8 bf16 (4 VGPRs)
typedef __attribute__((ext_vector_type(4))) float ffrag;  // 4 fp32 acc

__device__ __forceinline__ ushort f2bf(float f) {  // fp32 -> bf16 RNE
  uint u = __float_as_uint(f);
  uint r = u + 0x7FFFu + ((u >> 16) & 1u);
  return (ushort)(r >> 16);
}
__device__ __forceinline__ float bf2f(ushort h) {
  return __uint_as_float((uint)h << 16);
}

// ---------------- prep: wsplit(W_news) | wsplit(W_company) | count histogram ----------------
__global__ void prep_kernel(const float* __restrict__ Wn, const float* __restrict__ Wc,
                            ushort* __restrict__ WnHi, ushort* __restrict__ WnLo,
                            ushort* __restrict__ WcHi, ushort* __restrict__ WcLo,
                            const int* __restrict__ dst, int* __restrict__ counts, int E) {
  const int b = blockIdx.x, tid = threadIdx.x;
  if (b < 256) {
    int i = b * 256 + tid;
    float w = Wn[i];
    ushort h = f2bf(w);
    WnHi[i] = h;
    WnLo[i] = f2bf(w - bf2f(h));
  } else if (b < 512) {
    int i = (b - 256) * 256 + tid;
    float w = Wc[i];
    ushort h = f2bf(w);
    WcHi[i] = h;
    WcLo[i] = f2bf(w - bf2f(h));
  } else {
    int e = (b - 512) * 256 + tid;
    if (e < E) atomicAdd(&counts[dst[e]], 1);
  }
}

// single-block scan over C counts -> exclusive offsets[0..C], cursor copy
__global__ void scan_kernel(const int* __restrict__ counts, int* __restrict__ offsets,
                            int* __restrict__ cursor, int C) {
  __shared__ int wsum[4];
  int tid = threadIdx.x;
  int lane = tid & 63, wid = tid >> 6;
  int base = 0;
  for (int start = 0; start < C; start += 256) {
    int idx = start + tid;
    int val = (idx < C) ? counts[idx] : 0;
    int x = val;
#pragma unroll
    for (int off = 1; off < 64; off <<= 1) {
      int y = __shfl_up(x, off);
      if (lane >= off) x += y;
    }
    if (lane == 63) wsum[wid] = x;
    __syncthreads();
    int add = base;
    for (int w = 0; w < wid; ++w) add += wsum[w];
    if (idx < C) {
      int excl = add + x - val;
      offsets[idx] = excl;
      cursor[idx]  = excl;
    }
    int tot = wsum[0] + wsum[1] + wsum[2] + wsum[3];
    __syncthreads();
    base += tot;
  }
  if (tid == 0) offsets[C] = base;
}

__global__ void fill_kernel(const int* __restrict__ src, const int* __restrict__ dst,
                            int* __restrict__ cursor, int* __restrict__ srcs_sorted, int E) {
  int e = blockIdx.x * blockDim.x + threadIdx.x;
  if (e < E) {
    int d = dst[e];
    int pos = atomicAdd(&cursor[d], 1);
    srcs_sorted[pos] = src[e];
  }
}

// ---------------- MFMA GEMM: projbf[m][n] = bf16( sum_k X[m][k]*W[n][k] ) ----
// Block: 256 thr (4 waves), tile M=32 x N=256 (full), K=256.
// 4 blocks/CU target: LDS 16.9 KB, VGPR cap 128 via launch_bounds(256,4).
// Wave w owns n in [64w,64w+64): 2 mtiles x 4 ntiles, hi+lo products.
__global__ __launch_bounds__(256, 4) void gemm_mfma2(
    const float* __restrict__ X, const ushort* __restrict__ Whi,
    const ushort* __restrict__ Wlo, ushort* __restrict__ projbf,
    ushort* __restrict__ xbf, int M) {
  constexpr int PITCH = 264;           // ushorts per LDS row (528B = 33*16B)
  __shared__ ushort Xs[32 * PITCH];    // 16.9 KB
  const int tid = threadIdx.x;
  const int wave = tid >> 6, lane = tid & 63;
  const int q = lane >> 4, nidx = lane & 15;
  const int row0 = blockIdx.x * 32;

  // ---- stage 32x256 X tile (fp32 -> bf16), fully coalesced ----
#pragma unroll
  for (int it = 0; it < 4; ++it) {
    const int flat = it * 2048 + tid * 8;
    const int r = flat >> 8, k = flat & 255;
    int gr = row0 + r;
    if (gr >= M) gr = M - 1;  // clamp: duplicate row, stores guarded/idempotent
    const float4 x0 = *(const float4*)(X + (size_t)gr * H + k);
    const float4 x1 = *(const float4*)(X + (size_t)gr * H + k + 4);
    bfrag xb;
    xb[0] = (short)f2bf(x0.x); xb[1] = (short)f2bf(x0.y);
    xb[2] = (short)f2bf(x0.z); xb[3] = (short)f2bf(x0.w);
    xb[4] = (short)f2bf(x1.x); xb[5] = (short)f2bf(x1.y);
    xb[6] = (short)f2bf(x1.z); xb[7] = (short)f2bf(x1.w);
    *(bfrag*)&Xs[r * PITCH + k] = xb;
    if (xbf) *(bfrag*)(xbf + (size_t)gr * H + k) = xb;
  }
  __syncthreads();  // the only barrier

  ffrag acc[2][4];
#pragma unroll
  for (int i = 0; i < 2; ++i)
#pragma unroll
    for (int t = 0; t < 4; ++t) acc[i][t] = (ffrag)(0.f);

#pragma unroll
  for (int ks = 0; ks < 8; ++ks) {
    const int k0 = ks * 32;
    bfrag a[2];
#pragma unroll
    for (int i = 0; i < 2; ++i)
      a[i] = *(const bfrag*)&Xs[(16 * i + nidx) * PITCH + k0 + q * 8];
    bfrag bhi[4], blo[4];
#pragma unroll
    for (int t = 0; t < 4; ++t) {
      const size_t off = (size_t)(wave * 64 + t * 16 + nidx) * H + k0 + q * 8;
      bhi[t] = *(const bfrag*)(Whi + off);
      blo[t] = *(const bfrag*)(Wlo + off);
    }
#pragma unroll
    for (int i = 0; i < 2; ++i)
#pragma unroll
      for (int t = 0; t < 4; ++t) {
        acc[i][t] = __builtin_amdgcn_mfma_f32_16x16x32_bf16(a[i], bhi[t], acc[i][t], 0, 0, 0);
        acc[i][t] = __builtin_amdgcn_mfma_f32_16x16x32_bf16(a[i], blo[t], acc[i][t], 0, 0, 0);
      }
  }

  // ---- epilogue: C/D layout col=lane&15, row=q*4+reg; write bf16 ----
#pragma unroll
  for (int i = 0; i < 2; ++i)
#pragma unroll
    for (int r = 0; r < 4; ++r) {
      const int grow = row0 + 16 * i + q * 4 + r;
      if (grow < M) {
#pragma unroll
        for (int t = 0; t < 4; ++t)
          projbf[(size_t)grow * H + wave * 64 + t * 16 + nidx] = f2bf(acc[i][t][r]);
      }
    }
}

// ---------------- fused flash edge kernel: scores + online softmax + aggregate ----------------
__device__ __forceinline__ float fast_tanh(float x) {
  float e = __expf(2.f * x);
  return 1.f - 2.f / (e + 1.f);
}

// tanh(p + cq) . vv over this lane's 4 cols, then 64-lane butterfly sum
__device__ __forceinline__ float score_dot(ushort4 p, float4 cq, float4 vv) {
  float r = fast_tanh(bf2f(p.x) + cq.x) * vv.x + fast_tanh(bf2f(p.y) + cq.y) * vv.y +
            fast_tanh(bf2f(p.z) + cq.z) * vv.z + fast_tanh(bf2f(p.w) + cq.w) * vv.w;
#pragma unroll
  for (int off = 32; off > 0; off >>= 1) r += __shfl_xor(r, off);
  return r;  // all lanes hold the total
}

__global__ __launch_bounds__(256) void edge_flash_kernel(
    const ushort* __restrict__ news_projbf, const ushort* __restrict__ company_projbf,
    const float* __restrict__ v, const int* __restrict__ offsets,
    const int* __restrict__ srcs, const ushort* __restrict__ news_xbf,
    float* __restrict__ out) {
  const int c = blockIdx.x;
  const int tid = threadIdx.x, lane = tid & 63, wid = tid >> 6;
  __shared__ float cp[H];
  __shared__ float mW[4], lW[4];
  __shared__ float OW[4][H];  // 4 KB
  cp[tid] = bf2f(company_projbf[(size_t)c * H + tid]);
  __syncthreads();
  const float4 vv = *(const float4*)(v + lane * 4);
  const float4 cq = *(const float4*)&cp[lane * 4];
  const int beg = offsets[c], end = offsets[c + 1];

  float m = -INFINITY, l = 0.f;
  float4 O = make_float4(0.f, 0.f, 0.f, 0.f);

  // ---- pipelined pair loop: wave handles edges (beg+2*wid + 8k, +1) ----
  int i = beg + wid * 2;
  if (i + 1 < end) {
    int s0 = srcs[i], s1 = srcs[i + 1];
    ushort4 p0 = *(const ushort4*)(news_projbf + (size_t)s0 * H + lane * 4);
    ushort4 p1 = *(const ushort4*)(news_projbf + (size_t)s1 * H + lane * 4);
    ushort4 x0 = *(const ushort4*)(news_xbf + (size_t)s0 * H + lane * 4);
    ushort4 x1 = *(const ushort4*)(news_xbf + (size_t)s1 * H + lane * 4);
    for (;;) {
      const int inext = i + 8;
      const bool more = (inext + 1 < end);  // wave-uniform
      ushort4 np0, np1, nx0, nx1;
      if (more) {  // prefetch next pair while computing current
        int t0 = srcs[inext], t1 = srcs[inext + 1];
        np0 = *(const ushort4*)(news_projbf + (size_t)t0 * H + lane * 4);
        np1 = *(const ushort4*)(news_projbf + (size_t)t1 * H + lane * 4);
        nx0 = *(const ushort4*)(news_xbf + (size_t)t0 * H + lane * 4);
        nx1 = *(const ushort4*)(news_xbf + (size_t)t1 * H + lane * 4);
      }
      const float sa = score_dot(p0, cq, vv);
      const float sb = score_dot(p1, cq, vv);
      const float mnew = fmaxf(m, fmaxf(sa, sb));
      const float alpha = __expf(m - mnew);  // first iter: exp(-inf)=0
      const float pa = __expf(sa - mnew);
      const float pb = __expf(sb - mnew);
      l = l * alpha + pa + pb;
      O.x = O.x * alpha + pa * bf2f(x0.x) + pb * bf2f(x1.x);
      O.y = O.y * alpha + pa * bf2f(x0.y) + pb * bf2f(x1.y);
      O.z = O.z * alpha + pa * bf2f(x0.z) + pb * bf2f(x1.z);
      O.w = O.w * alpha + pa * bf2f(x0.w) + pb * bf2f(x1.w);
      m = mnew;
      i = inext;
      if (!more) break;
      p0 = np0; p1 = np1; x0 = nx0; x1 = nx1;
    }
  }
  if (i < end) {  // trailing single edge
    const int s0 = srcs[i];
    const ushort4 p0 = *(const ushort4*)(news_projbf + (size_t)s0 * H + lane * 4);
    const ushort4 x0 = *(const ushort4*)(news_xbf + (size_t)s0 * H + lane * 4);
    const float sa = score_dot(p0, cq, vv);
    const float mnew = fmaxf(m, sa);
    const float alpha = __expf(m - mnew);
    const float pa = __expf(sa - mnew);
    l = l * alpha + pa;
    O.x = O.x * alpha + pa * bf2f(x0.x);
    O.y = O.y * alpha + pa * bf2f(x0.y);
    O.z = O.z * alpha + pa * bf2f(x0.z);
    O.w = O.w * alpha + pa * bf2f(x0.w);
    m = mnew;
  }

  // ---- merge 4 waves ----
  if (lane == 0) { mW[wid] = m; lW[wid] = l; }
  *(float4*)&OW[wid][lane * 4] = O;
  __syncthreads();
  const float mstar = fmaxf(fmaxf(mW[0], mW[1]), fmaxf(mW[2], mW[3]));
  float denom = 0.f, val = 0.f;
#pragma unroll
  for (int w = 0; w < 4; ++w) {
    const float sc = (lW[w] > 0.f) ? __expf(mW[w] - mstar) : 0.f;
    denom += lW[w] * sc;
    val += OW[w][tid] * sc;
  }
  out[(size_t)c * H + tid] = val / fmaxf(denom, 1e-9f);
}

// ---------------- launch ----------------
extern "C" void kernel_launch(void* const* d_in, const int* in_sizes, int n_in,
                              void* d_out, int out_size, void* d_ws, size_t ws_size,
                              hipStream_t stream) {
  const float* news_x    = (const float*)d_in[0];
  const float* company_x = (const float*)d_in[1];
  const float* W_news    = (const float*)d_in[2];
  const float* W_company = (const float*)d_in[3];
  const float* v         = (const float*)d_in[4];
  const int*   src       = (const int*)d_in[5];
  const int*   dst       = (const int*)d_in[6];
  const int N = in_sizes[0] / H;
  const int C = in_sizes[1] / H;
  const int E = in_sizes[5];
  float* out = (float*)d_out;

  char* p = (char*)d_ws;
  ushort* news_projbf    = (ushort*)p; p += (size_t)N * H * sizeof(ushort);
  ushort* news_xbf       = (ushort*)p; p += (size_t)N * H * sizeof(ushort);
  ushort* company_projbf = (ushort*)p; p += (size_t)C * H * sizeof(ushort);
  int*    srcs_sorted    = (int*)p;    p += (size_t)E * sizeof(int);
  ushort* Wn_hi          = (ushort*)p; p += (size_t)H * H * sizeof(ushort);
  ushort* Wn_lo          = (ushort*)p; p += (size_t)H * H * sizeof(ushort);
  ushort* Wc_hi          = (ushort*)p; p += (size_t)H * H * sizeof(ushort);
  ushort* Wc_lo          = (ushort*)p; p += (size_t)H * H * sizeof(ushort);
  int*    counts         = (int*)p;    p += (size_t)C * sizeof(int);
  int*    offsets        = (int*)p;    p += (size_t)(C + 1) * sizeof(int);
  int*    cursor         = (int*)p;    p += (size_t)C * sizeof(int);

  hipMemsetAsync(counts, 0, (size_t)C * sizeof(int), stream);
  prep_kernel<<<512 + (E + 255) / 256, 256, 0, stream>>>(
      W_news, W_company, Wn_hi, Wn_lo, Wc_hi, Wc_lo, dst, counts, E);
  scan_kernel<<<1, 256, 0, stream>>>(counts, offsets, cursor, C);
  fill_kernel<<<(E + 255) / 256, 256, 0, stream>>>(src, dst, cursor, srcs_sorted, E);

  gemm_mfma2<<<(C + 31) / 32, 256, 0, stream>>>(company_x, Wc_hi, Wc_lo,
                                                company_projbf, (ushort*)nullptr, C);
  gemm_mfma2<<<(N + 31) / 32, 256, 0, stream>>>(news_x, Wn_hi, Wn_lo,
                                                news_projbf, news_xbf, N);

  edge_flash_kernel<<<C, 256, 0, stream>>>(news_projbf, company_projbf, v, offsets,
                                           srcs_sorted, news_xbf, out);
}